// Round 6
// baseline (471.622 us; speedup 1.0000x reference)
//
#include <hip/hip_runtime.h>

// MHA: cvt fp32->bf16 -> QKV GEMM (128x256 pipelined bf16 MFMA, fused RoPE)
//      -> MFMA flash attention (K direct from L2, fp32 out)
// B=2 S=2048 E=2048 NH=16 HD=128 ROTARY=32 base=1e4 NEG_INF=-1e4
#define B_    2
#define S_    2048
#define E_    2048
#define NH_   16
#define HD_   128
#define NQKV_ 6144
#define M_    4096
#define XN_   (M_ * E_)          // 8388608 X elements
#define NPAN  (E_ / 32)          // 64 K-panels of 32

typedef short bf16x8 __attribute__((ext_vector_type(8)));   // 8 bf16 (4 VGPRs)
typedef float f32x4  __attribute__((ext_vector_type(4)));   // MFMA C/D

typedef const __attribute__((address_space(1))) void* gas_t; // global addrspace
typedef __attribute__((address_space(3))) void*       las_t; // LDS addrspace

__device__ inline float b2f(unsigned short u) {
    return __uint_as_float(((unsigned int)u) << 16);
}
__device__ inline unsigned short f2b(float f) {             // RNE f32->bf16
    unsigned int x = __float_as_uint(f);
    x = x + 0x7fffu + ((x >> 16) & 1u);
    return (unsigned short)(x >> 16);
}
__device__ inline unsigned int pk2(float lo, float hi) {
    return (unsigned int)f2b(lo) | ((unsigned int)f2b(hi) << 16);
}

// ---------------------------------------------------------------------------
// Kernel 0: one-shot fp32 -> bf16 of X (8.39M) and W (12.58M) into workspace.
// ---------------------------------------------------------------------------
__global__ __launch_bounds__(256) void cvt_bf16(
    const float* __restrict__ X,
    const float* __restrict__ W,
    unsigned short* __restrict__ O)      // [XN_ of X][W follows]
{
    const long i = (long)(blockIdx.x * 256 + threadIdx.x) * 8;
    const float* src = (i < XN_) ? (X + i) : (W + (i - XN_));
    const float4 a = *(const float4*)(src);
    const float4 b = *(const float4*)(src + 4);
    uint4 o = { pk2(a.x, a.y), pk2(a.z, a.w), pk2(b.x, b.y), pk2(b.z, b.w) };
    *(uint4*)(O + i) = o;
}

// ---------------------------------------------------------------------------
// Kernel 1: QKV = Xb(4096x2048 bf16) * Wb^T + bias, RoPE fused in epilogue.
// ROUND-5: tile 128x256 -> grid 32x24 = 768 blocks = EXACTLY 3 full dispatch
// rounds on 256 CUs (round-4's 384 = 2 rounds, 2nd half-empty -> 25% waste).
// 512 threads (8 waves, 2M x 4N), wave output 64x64 (acc[4][4]).
// K in 32-wide panels, 4 LDS slots (96 KiB), ONE phase per panel:
//   {8 ds_read; stage A,B(p+3); vmcnt(tail-aware); barrier;
//    setprio(1) 16 MFMA setprio(0); barrier}
// vmcnt invariant (established at panel p for p+1): after stage(p+3), the
// loads newer than A/B(p+1) are A/B(p+2),A/B(p+3) = 6 -> vmcnt(6).
// Tail (no p+3 stage): newer = A/B(p+2) = 3 -> vmcnt(3); then vmcnt(0).
// (Round-4 used the steady-state count unconditionally — latent race.)
// LDS layout: [row][4 k-octets of 16B], octet ko' = ko ^ ((row>>1)&3),
// applied on the global SOURCE (gload_lds writes linearly) and on ds_read
// (both-sides involution) -> b128 frag reads spread over 8 bank groups.
// WAR: stage(p+3) writes slot (p-1)&3; p-1's reads retired before its
// closing barrier; stage issues after it.
// ---------------------------------------------------------------------------
__global__ __launch_bounds__(512, 2) void qkv_gemm(
    const unsigned short* __restrict__ Xb,   // bf16 [4096][2048]
    const unsigned short* __restrict__ Wb,   // bf16 [6144][2048]
    const float* __restrict__ bias,
    unsigned short* __restrict__ qb,
    unsigned short* __restrict__ kb,
    unsigned short* __restrict__ vb)
{
    __shared__ __align__(16) unsigned short As[4][128 * 32];  // 32 KiB
    __shared__ __align__(16) unsigned short Bs[4][256 * 32];  // 64 KiB

    const int t    = threadIdx.x;            // 0..511
    const int lane = t & 63;
    const int w    = t >> 6;                 // 0..7
    const int wr   = w >> 2;                 // 0..1  (m half, 64 rows)
    const int wc   = w & 3;                  // 0..3  (n quarter, 64 cols)
    const int quad = (lane >> 4) & 3;
    const int l16  = lane & 15;

    // XCD-aware bijective swizzle: 768 = 8 * 96
    const int wg = ((int)blockIdx.x & 7) * 96 + ((int)blockIdx.x >> 3);
    const int m0 = (wg / 24) * 128;          // 0..31 -> 128-row tiles
    const int n0 = (wg % 24) * 256;          // 0..23 -> 256-col tiles

    // --- staging. A panel (128x32) = 8 KB = 1 block-call; B (256x32) = 2.
    // 16B-unit u -> (row = u>>2, koLDS = u&3); global octet = koLDS^((row>>1)&3).
    auto stageA = [&](int p) {
        const int sl = p & 3;
        const int k0 = p * 32;
        const int ub  = w * 64;
        const int u   = ub + lane;
        const int row = u >> 2;
        const int ko  = (u & 3) ^ ((row >> 1) & 3);
        __builtin_amdgcn_global_load_lds(
            (gas_t)(Xb + (size_t)(m0 + row) * E_ + k0 + ko * 8),
            (las_t)&As[sl][ub * 8], 16, 0, 0);
    };
    auto stageB = [&](int p) {
        const int sl = p & 3;
        const int k0 = p * 32;
        #pragma unroll
        for (int c = 0; c < 2; c++) {
            const int ub  = c * 512 + w * 64;
            const int u   = ub + lane;
            const int row = u >> 2;
            const int ko  = (u & 3) ^ ((row >> 1) & 3);
            __builtin_amdgcn_global_load_lds(
                (gas_t)(Wb + (size_t)(n0 + row) * E_ + k0 + ko * 8),
                (las_t)&Bs[sl][ub * 8], 16, 0, 0);
        }
    };

    f32x4 acc[4][4];
    #pragma unroll
    for (int i = 0; i < 4; i++)
        #pragma unroll
        for (int j = 0; j < 4; j++)
            #pragma unroll
            for (int r = 0; r < 4; r++) acc[i][j][r] = 0.0f;

    // prologue: stage panels 0..2, full drain once -> panels 0..2 landed
    stageA(0); stageB(0);
    stageA(1); stageB(1);
    stageA(2); stageB(2);
    asm volatile("s_waitcnt vmcnt(0)" ::: "memory");
    __builtin_amdgcn_s_barrier();

    for (int p = 0; p < NPAN; p++) {
        const int sl = p & 3;
        bf16x8 af[4], bfv[4];

        #pragma unroll
        for (int mf = 0; mf < 4; mf++) {
            const int row = wr * 64 + mf * 16 + l16;
            af[mf] = *(const bf16x8*)&As[sl][row * 32 + (quad ^ ((row >> 1) & 3)) * 8];
        }
        #pragma unroll
        for (int nf = 0; nf < 4; nf++) {
            const int rb = wc * 64 + nf * 16 + l16;
            bfv[nf] = *(const bf16x8*)&Bs[sl][rb * 32 + (quad ^ ((rb >> 1) & 3)) * 8];
        }

        if (p + 3 < NPAN) {
            stageA(p + 3); stageB(p + 3);
            asm volatile("s_waitcnt vmcnt(6)" ::: "memory");   // p+1 landed
        } else if (p + 2 < NPAN) {
            asm volatile("s_waitcnt vmcnt(3)" ::: "memory");   // p+1 landed
        } else {
            asm volatile("s_waitcnt vmcnt(0)" ::: "memory");
        }
        __builtin_amdgcn_s_barrier();
        __builtin_amdgcn_s_setprio(1);
        #pragma unroll
        for (int mf = 0; mf < 4; mf++)
            #pragma unroll
            for (int nf = 0; nf < 4; nf++)
                acc[mf][nf] = __builtin_amdgcn_mfma_f32_16x16x32_bf16(
                    af[mf], bfv[nf], acc[mf][nf], 0, 0, 0);
        __builtin_amdgcn_s_setprio(0);
        __builtin_amdgcn_s_barrier();
    }

    // ---- epilogue: bias, fused RoPE, bf16 scatter stores (no LDS use).
    const int which = n0 >> 11;                   // 0=q 1=k 2=v (const/block)
    unsigned short* dst = (which == 0) ? qb : ((which == 1) ? kb : vb);

    float bv[4];
    #pragma unroll
    for (int nf = 0; nf < 4; nf++) bv[nf] = bias[n0 + wc * 64 + nf * 16 + l16];
    #pragma unroll
    for (int mi = 0; mi < 4; mi++)
        #pragma unroll
        for (int nf = 0; nf < 4; nf++)
            #pragma unroll
            for (int r = 0; r < 4; r++) acc[mi][nf][r] += bv[nf];

    // RoPE: tile spans 2 heads; head-local d<64 quarters are wc==0 (head A)
    // and wc==2 (head B). Pairs (d=l16, d+16) live in acc[mi][0]/acc[mi][1].
    if ((wc & 1) == 0 && which < 2) {
        const float inv = exp2f(-0.83048202372184059f * (float)l16); // 1e4^(-d/16)
        #pragma unroll
        for (int mi = 0; mi < 4; mi++) {
            #pragma unroll
            for (int r = 0; r < 4; r++) {
                const int m = m0 + wr * 64 + mi * 16 + quad * 4 + r;
                const int sdx = m & (S_ - 1);
                float c, sn;
                __sincosf((float)sdx * inv, &sn, &c);
                const float u1 = acc[mi][0][r], u2 = acc[mi][1][r];
                acc[mi][0][r] = u1 * c - u2 * sn;
                acc[mi][1][r] = u1 * sn + u2 * c;
            }
        }
    }

    #pragma unroll
    for (int nf = 0; nf < 4; nf++) {
        const int hh = ((n0 + wc * 64 + nf * 16) >> 7) & 15;
        const int d  = ((wc * 64 + nf * 16) & 127) + l16;
        #pragma unroll
        for (int mi = 0; mi < 4; mi++) {
            #pragma unroll
            for (int r = 0; r < 4; r++) {
                const int m   = m0 + wr * 64 + mi * 16 + quad * 4 + r;
                const int bb  = m >> 11;
                const int sdx = m & (S_ - 1);
                dst[((size_t)(bb * NH_ + hh) * S_ + sdx) * HD_ + d] =
                    f2b(acc[mi][nf][r]);
            }
        }
    }
}

// ---------------------------------------------------------------------------
// Kernel 2: MFMA causal flash attention. ROUND-5: K read DIRECTLY from
// global (L2-resident: FETCH shows ~ideal 36 MB) instead of LDS staging.
// Removes per-iter: 4 b128 LDS writes + 16 b128 LDS reads per wave (~40% of
// LDS pipe) + K prefetch regs. LDS 45 -> 27.6 KB -> 5 blocks/CU (all 1024
// blocks co-resident). kf read pattern identical to the old staged read:
// K[s0 + nb*16 + l16][c*32 + quad*8 ..] (16 rows x 64B contiguous per instr).
// V path, softmax, PV unchanged. Epilogue Ow split into two 64-col passes
// (OSTR 68, wave-private) to keep the union small.
// Layouts (HW-verified 16x16x32_bf16): A[m=lane&15][k=quad*8+j];
// C/D row=quad*4+reg, col=lane&15.
// ---------------------------------------------------------------------------
#define VSTR 72
#define PSTR 72
#define OSTR 68

__global__ __launch_bounds__(256, 4) void attn_mfma(
    const unsigned short* __restrict__ qb,
    const unsigned short* __restrict__ kb,
    const unsigned short* __restrict__ vb,
    float* __restrict__ out)
{
    union SM {
        struct {
            unsigned short Vt[128 * VSTR];     // 18432 B
            unsigned short Ps[4 * 16 * PSTR];  //  9216 B
        } a;                                   // 27648 B total
        float Ow[4 * 16 * OSTR];               // 17408 B (epilogue reuse)
    };
    __shared__ __align__(16) SM sm;
    unsigned short* Vt = sm.a.Vt;
    unsigned short* Ps = sm.a.Ps;

    const int bid  = blockIdx.x;
    const int qt   = 31 - (bid >> 5);       // 64-row q-tile, heavy-first
    const int bh   = bid & 31;
    const int b    = bh >> 4;
    const int h    = bh & 15;
    const int t    = threadIdx.x;
    const int lane = t & 63;
    const int w    = t >> 6;
    const int quad = lane >> 4;
    const int l16  = lane & 15;

    const int wrow0  = qt * 64 + w * 16;    // wave q-row base (16 rows)
    const int ntiles = qt + 1;              // K tiles of 64

    unsigned short* Pw = Ps + w * 16 * PSTR;

    // V staging map (256 threads)
    const int vq = t & 31, vd0 = (t >> 5) * 16;  // s-pair, d-block

    // Q A-fragments from global: k = c*32 + quad*8 + j
    bf16x8 qf[4];
    {
        const unsigned short* qp =
            qb + ((size_t)(bh * S_ + wrow0 + l16)) * HD_ + quad * 8;
        #pragma unroll
        for (int c = 0; c < 4; c++)
            qf[c] = *(const bf16x8*)(qp + c * 32);
    }

    // K base for direct fragment loads (L2-resident)
    const unsigned short* kgb =
        kb + ((size_t)(bh * S_)) * HD_ + quad * 8;

    f32x4 of[8];
    #pragma unroll
    for (int db = 0; db < 8; db++)
        #pragma unroll
        for (int r = 0; r < 4; r++) of[db][r] = 0.0f;
    float mr[4], lr[4];
    #pragma unroll
    for (int r = 0; r < 4; r++) { mr[r] = -1e30f; lr[r] = 0.0f; }

    // log2-domain softmax: scale' = (1/sqrt(128))*log2(e), mask' = -1e4*log2(e)
    const float scale2 = 0.12751744459892879f;
    const float mneg2  = -14426.950408889634f;

    // V prefetch registers
    uint4 v0a, v0b, v1a, v1b;

    auto issue_tile = [&](int kt2) {
        const int s2 = kt2 * 64;
        const unsigned short* vg = vb + ((size_t)(bh * S_ + s2 + 2 * vq)) * HD_ + vd0;
        v0a = *(const uint4*)(vg);
        v0b = *(const uint4*)(vg + 8);
        v1a = *(const uint4*)(vg + HD_);
        v1b = *(const uint4*)(vg + HD_ + 8);
    };

    issue_tile(0);

    for (int kt = 0; kt < ntiles; kt++) {
        const int s0 = kt * 64;
        __syncthreads();                  // prior iter's LDS readers done
        // ---- V tile -> LDS transposed: Vt[d][s], s-pairs packed as b32
        {
            unsigned int r0[8] = { v0a.x, v0a.y, v0a.z, v0a.w,
                                   v0b.x, v0b.y, v0b.z, v0b.w };
            unsigned int r1[8] = { v1a.x, v1a.y, v1a.z, v1a.w,
                                   v1b.x, v1b.y, v1b.z, v1b.w };
            #pragma unroll
            for (int j = 0; j < 16; j++) {
                const int u = j >> 1;
                unsigned int pk;
                if ((j & 1) == 0)
                    pk = (r0[u] & 0xffffu) | (r1[u] << 16);
                else
                    pk = (r0[u] >> 16) | (r1[u] & 0xffff0000u);
                *(unsigned int*)&Vt[(vd0 + j) * VSTR + 2 * vq] = pk;
            }
        }
        __syncthreads();

        if (kt + 1 < ntiles) issue_tile(kt + 1);

        // ---- S = Q K^T : kf direct from global (per-c batches of 4)
        f32x4 sf[4];
        #pragma unroll
        for (int nb = 0; nb < 4; nb++)
            #pragma unroll
            for (int r = 0; r < 4; r++) sf[nb][r] = 0.0f;
        {
            const unsigned short* kg = kgb + (size_t)(s0 + l16) * HD_;
            #pragma unroll
            for (int c = 0; c < 4; c++) {
                bf16x8 kf[4];
                #pragma unroll
                for (int nb = 0; nb < 4; nb++)
                    kf[nb] = *(const bf16x8*)(kg + (size_t)(nb * 16) * HD_ + c * 32);
                #pragma unroll
                for (int nb = 0; nb < 4; nb++)
                    sf[nb] = __builtin_amdgcn_mfma_f32_16x16x32_bf16(
                        qf[c], kf[nb], sf[nb], 0, 0, 0);
            }
        }

        // ---- scale + causal mask, log2 domain
        const bool need_mask = (s0 + 63 > wrow0);
        {
            const int qr0 = wrow0 + quad * 4;
            #pragma unroll
            for (int nb = 0; nb < 4; nb++) {
                const int kcol = s0 + nb * 16 + l16;
                #pragma unroll
                for (int r = 0; r < 4; r++) {
                    float s = sf[nb][r] * scale2;
                    if (need_mask && kcol > qr0 + r) s += mneg2;
                    sf[nb][r] = s;
                }
            }
        }

        // ---- online softmax (max reduce over 16-lane group; lr partials;
        //      rescale deferred when no row max grew)
        {
            float mt4[4];
            #pragma unroll
            for (int r = 0; r < 4; r++) {
                float mt = fmaxf(fmaxf(sf[0][r], sf[1][r]),
                                 fmaxf(sf[2][r], sf[3][r]));
                mt = fmaxf(mt, __shfl_xor(mt, 1));
                mt = fmaxf(mt, __shfl_xor(mt, 2));
                mt = fmaxf(mt, __shfl_xor(mt, 4));
                mt = fmaxf(mt, __shfl_xor(mt, 8));
                mt4[r] = mt;
            }
            const bool grew = (mt4[0] > mr[0]) || (mt4[1] > mr[1]) ||
                              (mt4[2] > mr[2]) || (mt4[3] > mr[3]);
            if (__any(grew)) {
                float alpha[4];
                #pragma unroll
                for (int r = 0; r < 4; r++) {
                    const float mnew = fmaxf(mr[r], mt4[r]);
                    alpha[r] = __builtin_amdgcn_exp2f(mr[r] - mnew);
                    mr[r] = mnew;
                    lr[r] *= alpha[r];
                }
                #pragma unroll
                for (int db = 0; db < 8; db++)
                    #pragma unroll
                    for (int r = 0; r < 4; r++) of[db][r] *= alpha[r];
            }
            #pragma unroll
            for (int r = 0; r < 4; r++) {
                float rs = 0.0f;
                #pragma unroll
                for (int nb = 0; nb < 4; nb++) {
                    float p = __builtin_amdgcn_exp2f(sf[nb][r] - mr[r]);
                    sf[nb][r] = p;
                    rs += p;
                }
                lr[r] += rs;       // per-lane partial; reduced in epilogue
            }

            // P: C-layout -> wave-private LDS [m][s]
            #pragma unroll
            for (int nb = 0; nb < 4; nb++)
                #pragma unroll
                for (int r = 0; r < 4; r++)
                    Pw[(quad * 4 + r) * PSTR + nb * 16 + l16] = f2b(sf[nb][r]);
        }

        // ---- O += P V
        #pragma unroll
        for (int kc = 0; kc < 2; kc++) {
            bf16x8 pf = *(const bf16x8*)&Pw[l16 * PSTR + kc * 32 + quad * 8];
            #pragma unroll
            for (int db = 0; db < 8; db++) {
                bf16x8 vf = *(const bf16x8*)&Vt[(db * 16 + l16) * VSTR + kc * 32 + quad * 8];
                of[db] = __builtin_amdgcn_mfma_f32_16x16x32_bf16(
                    pf, vf, of[db], 0, 0, 0);
            }
        }
    }

    // ---- epilogue: lane-reduce lr, normalize; two 64-col passes through
    // wave-private Ow (16 x 68 fp32), coalesced float4 stores.
    float* Ow = sm.Ow + w * 16 * OSTR;
    __syncthreads();                       // all readers of Vt/Ps done
    float inv[4];
    #pragma unroll
    for (int r = 0; r < 4; r++) {
        float ls = lr[r];
        ls += __shfl_xor(ls, 1);
        ls += __shfl_xor(ls, 2);
        ls += __shfl_xor(ls, 4);
        ls += __shfl_xor(ls, 8);
        inv[r] = 1.0f / ls;
    }
    #pragma unroll
    for (int half = 0; half < 2; half++) {
        #pragma unroll
        for (int db4 = 0; db4 < 4; db4++) {
            const int db = half * 4 + db4;
            #pragma unroll
            for (int r = 0; r < 4; r++)
                Ow[(quad * 4 + r) * OSTR + db4 * 16 + l16] = of[db][r] * inv[r];
        }
        #pragma unroll
        for (int rg = 0; rg < 4; rg++) {
            const int rowl = rg * 4 + quad;
            float* op = out + ((size_t)(b * S_ + wrow0 + rowl)) * E_ + h * HD_;
            float4 v4 = *(const float4*)&Ow[rowl * OSTR + l16 * 4];
            *(float4*)(op + half * 64 + l16 * 4) = v4;
        }
    }
}

// ---------------------------------------------------------------------------
extern "C" void kernel_launch(void* const* d_in, const int* in_sizes, int n_in,
                              void* d_out, int out_size, void* d_ws, size_t ws_size,
                              hipStream_t stream)
{
    const float* x    = (const float*)d_in[0];   // fp32 (B,S,E)
    const float* W    = (const float*)d_in[1];   // fp32 (6144,2048)
    const float* bias = (const float*)d_in[2];   // fp32 (6144,)
    float* out = (float*)d_out;                  // fp32 (B,S,E)

    const size_t per = (size_t)B_ * NH_ * S_ * HD_;               // 8388608
    unsigned short* qb = (unsigned short*)d_ws;                   // [B][NH][S][HD]
    unsigned short* kb = qb + per;                                // [B][NH][S][HD]
    unsigned short* vb = kb + per;                                // [B][NH][S][HD]
    unsigned short* Xb = vb + per;                                // bf16 X  (16.8 MB)
    unsigned short* Wb = Xb + (size_t)XN_;                        // bf16 W  (25.2 MB)

    const int cvt_elems = XN_ + NQKV_ * E_;                       // 20971520
    cvt_bf16<<<cvt_elems / (256 * 8), 256, 0, stream>>>(x, W, Xb);

    dim3 gemm_grid((M_ / 128) * (NQKV_ / 256));                   // 32*24 = 768
    qkv_gemm<<<gemm_grid, 512, 0, stream>>>(Xb, Wb, bias, qb, kb, vb);

    attn_mfma<<<dim3(32 * 32), 256, 0, stream>>>(qb, kb, vb, out);
}

// Round 7
// 368.585 us; speedup vs baseline: 1.2795x; 1.2795x over previous
//
#include <hip/hip_runtime.h>

// MHA: cvt fp32->bf16 -> QKV GEMM (128x256, 3-slot pipelined bf16 MFMA, fused
//      RoPE) -> MFMA flash attention (K LDS-staged + XOR swizzle, fp32 out)
// B=2 S=2048 E=2048 NH=16 HD=128 ROTARY=32 base=1e4 NEG_INF=-1e4
#define B_    2
#define S_    2048
#define E_    2048
#define NH_   16
#define HD_   128
#define NQKV_ 6144
#define M_    4096
#define XN_   (M_ * E_)          // 8388608 X elements
#define NPAN  (E_ / 32)          // 64 K-panels of 32

typedef short bf16x8 __attribute__((ext_vector_type(8)));   // 8 bf16 (4 VGPRs)
typedef float f32x4  __attribute__((ext_vector_type(4)));   // MFMA C/D

typedef const __attribute__((address_space(1))) void* gas_t; // global addrspace
typedef __attribute__((address_space(3))) void*       las_t; // LDS addrspace

__device__ inline float b2f(unsigned short u) {
    return __uint_as_float(((unsigned int)u) << 16);
}
__device__ inline unsigned short f2b(float f) {             // RNE f32->bf16
    unsigned int x = __float_as_uint(f);
    x = x + 0x7fffu + ((x >> 16) & 1u);
    return (unsigned short)(x >> 16);
}
__device__ inline unsigned int pk2(float lo, float hi) {
    return (unsigned int)f2b(lo) | ((unsigned int)f2b(hi) << 16);
}

// ---------------------------------------------------------------------------
// Kernel 0: one-shot fp32 -> bf16 of X (8.39M) and W (12.58M) into workspace.
// ---------------------------------------------------------------------------
__global__ __launch_bounds__(256) void cvt_bf16(
    const float* __restrict__ X,
    const float* __restrict__ W,
    unsigned short* __restrict__ O)      // [XN_ of X][W follows]
{
    const long i = (long)(blockIdx.x * 256 + threadIdx.x) * 8;
    const float* src = (i < XN_) ? (X + i) : (W + (i - XN_));
    const float4 a = *(const float4*)(src);
    const float4 b = *(const float4*)(src + 4);
    uint4 o = { pk2(a.x, a.y), pk2(a.z, a.w), pk2(b.x, b.y), pk2(b.z, b.w) };
    *(uint4*)(O + i) = o;
}

// ---------------------------------------------------------------------------
// Kernel 1: QKV = Xb(4096x2048 bf16) * Wb^T + bias, RoPE fused in epilogue.
// ROUND-6: 128x256 tile kept (768 blocks = 3 full rounds), LDS slots 4 -> 3
// (96 -> 72 KiB) so TWO blocks fit per CU: one block's prologue/epilogue now
// overlaps the other's main loop (round-5's 96 KiB = 1 block/CU = no overlap,
// measured ~150 us ~= no better than 256^2).
// Pipeline (depth-2 prefetch): per panel p
//   {8 ds_read(slot p%3); stage A,B(p+2); vmcnt(3); barrier;
//    setprio(1) 16 MFMA setprio(0); barrier}
// vmcnt invariant: after stage(p+2) the loads newer than A/B(p+1) are
// exactly stage(p+2)'s 3 calls -> vmcnt(3) ensures panel p+1 landed.
// Tail (no stage): vmcnt(0). Prologue stages 0,1 + vmcnt(0) + barrier.
// WAR: stage(p+2) writes slot (p-1)%3; panel p-1's ds_reads were consumed
// before its closing barrier; stage issues after that barrier.
// LDS layout: [row][4 k-octets of 16B], octet ko' = ko ^ ((row>>1)&3) applied
// on the global SOURCE (gload_lds writes linearly) and on ds_read.
// ---------------------------------------------------------------------------
__global__ __launch_bounds__(512, 4) void qkv_gemm(
    const unsigned short* __restrict__ Xb,   // bf16 [4096][2048]
    const unsigned short* __restrict__ Wb,   // bf16 [6144][2048]
    const float* __restrict__ bias,
    unsigned short* __restrict__ qb,
    unsigned short* __restrict__ kb,
    unsigned short* __restrict__ vb)
{
    __shared__ __align__(16) unsigned short As[3][128 * 32];  // 24 KiB
    __shared__ __align__(16) unsigned short Bs[3][256 * 32];  // 48 KiB

    const int t    = threadIdx.x;            // 0..511
    const int lane = t & 63;
    const int w    = t >> 6;                 // 0..7
    const int wr   = w >> 2;                 // 0..1  (m half, 64 rows)
    const int wc   = w & 3;                  // 0..3  (n quarter, 64 cols)
    const int quad = (lane >> 4) & 3;
    const int l16  = lane & 15;

    // XCD-aware bijective swizzle: 768 = 8 * 96
    const int wg = ((int)blockIdx.x & 7) * 96 + ((int)blockIdx.x >> 3);
    const int m0 = (wg / 24) * 128;          // 0..31 -> 128-row tiles
    const int n0 = (wg % 24) * 256;          // 0..23 -> 256-col tiles

    // --- staging. A panel (128x32) = 8 KB = 1 block-call; B (256x32) = 2.
    // 16B-unit u -> (row = u>>2, koLDS = u&3); global octet = koLDS^((row>>1)&3).
    auto stageA = [&](int p) {
        const int sl = p % 3;
        const int k0 = p * 32;
        const int ub  = w * 64;
        const int u   = ub + lane;
        const int row = u >> 2;
        const int ko  = (u & 3) ^ ((row >> 1) & 3);
        __builtin_amdgcn_global_load_lds(
            (gas_t)(Xb + (size_t)(m0 + row) * E_ + k0 + ko * 8),
            (las_t)&As[sl][ub * 8], 16, 0, 0);
    };
    auto stageB = [&](int p) {
        const int sl = p % 3;
        const int k0 = p * 32;
        #pragma unroll
        for (int c = 0; c < 2; c++) {
            const int ub  = c * 512 + w * 64;
            const int u   = ub + lane;
            const int row = u >> 2;
            const int ko  = (u & 3) ^ ((row >> 1) & 3);
            __builtin_amdgcn_global_load_lds(
                (gas_t)(Wb + (size_t)(n0 + row) * E_ + k0 + ko * 8),
                (las_t)&Bs[sl][ub * 8], 16, 0, 0);
        }
    };

    f32x4 acc[4][4];
    #pragma unroll
    for (int i = 0; i < 4; i++)
        #pragma unroll
        for (int j = 0; j < 4; j++)
            #pragma unroll
            for (int r = 0; r < 4; r++) acc[i][j][r] = 0.0f;

    // prologue: stage panels 0..1, full drain once -> panels 0..1 landed
    stageA(0); stageB(0);
    stageA(1); stageB(1);
    asm volatile("s_waitcnt vmcnt(0)" ::: "memory");
    __builtin_amdgcn_s_barrier();

    for (int p = 0; p < NPAN; p++) {
        const int sl = p % 3;
        bf16x8 af[4], bfv[4];

        #pragma unroll
        for (int mf = 0; mf < 4; mf++) {
            const int row = wr * 64 + mf * 16 + l16;
            af[mf] = *(const bf16x8*)&As[sl][row * 32 + (quad ^ ((row >> 1) & 3)) * 8];
        }
        #pragma unroll
        for (int nf = 0; nf < 4; nf++) {
            const int rb = wc * 64 + nf * 16 + l16;
            bfv[nf] = *(const bf16x8*)&Bs[sl][rb * 32 + (quad ^ ((rb >> 1) & 3)) * 8];
        }

        if (p + 2 < NPAN) {
            stageA(p + 2); stageB(p + 2);
            asm volatile("s_waitcnt vmcnt(3)" ::: "memory");   // p+1 landed
        } else {
            asm volatile("s_waitcnt vmcnt(0)" ::: "memory");   // tail
        }
        __builtin_amdgcn_s_barrier();
        __builtin_amdgcn_s_setprio(1);
        #pragma unroll
        for (int mf = 0; mf < 4; mf++)
            #pragma unroll
            for (int nf = 0; nf < 4; nf++)
                acc[mf][nf] = __builtin_amdgcn_mfma_f32_16x16x32_bf16(
                    af[mf], bfv[nf], acc[mf][nf], 0, 0, 0);
        __builtin_amdgcn_s_setprio(0);
        __builtin_amdgcn_s_barrier();
    }

    // ---- epilogue: bias, fused RoPE, bf16 scatter stores (no LDS use).
    const int which = n0 >> 11;                   // 0=q 1=k 2=v (const/block)
    unsigned short* dst = (which == 0) ? qb : ((which == 1) ? kb : vb);

    float bv[4];
    #pragma unroll
    for (int nf = 0; nf < 4; nf++) bv[nf] = bias[n0 + wc * 64 + nf * 16 + l16];
    #pragma unroll
    for (int mi = 0; mi < 4; mi++)
        #pragma unroll
        for (int nf = 0; nf < 4; nf++)
            #pragma unroll
            for (int r = 0; r < 4; r++) acc[mi][nf][r] += bv[nf];

    // RoPE: tile spans 2 heads; head-local d<64 quarters are wc==0 (head A)
    // and wc==2 (head B). Pairs (d=l16, d+16) live in acc[mi][0]/acc[mi][1].
    if ((wc & 1) == 0 && which < 2) {
        const float inv = exp2f(-0.83048202372184059f * (float)l16); // 1e4^(-d/16)
        #pragma unroll
        for (int mi = 0; mi < 4; mi++) {
            #pragma unroll
            for (int r = 0; r < 4; r++) {
                const int m = m0 + wr * 64 + mi * 16 + quad * 4 + r;
                const int sdx = m & (S_ - 1);
                float c, sn;
                __sincosf((float)sdx * inv, &sn, &c);
                const float u1 = acc[mi][0][r], u2 = acc[mi][1][r];
                acc[mi][0][r] = u1 * c - u2 * sn;
                acc[mi][1][r] = u1 * sn + u2 * c;
            }
        }
    }

    #pragma unroll
    for (int nf = 0; nf < 4; nf++) {
        const int hh = ((n0 + wc * 64 + nf * 16) >> 7) & 15;
        const int d  = ((wc * 64 + nf * 16) & 127) + l16;
        #pragma unroll
        for (int mi = 0; mi < 4; mi++) {
            #pragma unroll
            for (int r = 0; r < 4; r++) {
                const int m   = m0 + wr * 64 + mi * 16 + quad * 4 + r;
                const int bb  = m >> 11;
                const int sdx = m & (S_ - 1);
                dst[((size_t)(bb * NH_ + hh) * S_ + sdx) * HD_ + d] =
                    f2b(acc[mi][nf][r]);
            }
        }
    }
}

// ---------------------------------------------------------------------------
// Kernel 2: MFMA causal flash attention. ROUND-6: revert to the measured
// 141-us LDS-staged-K structure (round-5's K-direct-from-L2 was 231 us:
// 256B-stride lane access + 4x per-wave refetch at L2 latency). One change:
// Ks stride 136 -> 128 with XOR swizzle unit' = unit ^ (row&7) (16B units),
// applied on BOTH the staging write and the fragment read. Bank math: the
// 136-stride layout put K writes into 2 of 8 bank groups (4x serialize,
// ~6.5M of the 11.5M conflict cycles); swizzled 128-stride tiles all 32
// banks at the 8-phase minimum for both writes and reads.
// Layouts (HW-verified 16x16x32_bf16): A[m=lane&15][k=quad*8+j];
// C/D row=quad*4+reg, col=lane&15.
// ---------------------------------------------------------------------------
#define KSTR 128
#define VSTR 72
#define PSTR 72
#define OSTR 132

__global__ __launch_bounds__(256, 3) void attn_mfma(
    const unsigned short* __restrict__ qb,
    const unsigned short* __restrict__ kb,
    const unsigned short* __restrict__ vb,
    float* __restrict__ out)
{
    union SM {
        struct {
            unsigned short Ks[64 * KSTR];      // 16384 B
            unsigned short Vt[128 * VSTR];     // 18432 B
            unsigned short Ps[4 * 16 * PSTR];  //  9216 B
        } a;                                   // 44032 B total
        float Ow[4 * 16 * OSTR];               // 33792 B (epilogue reuse)
    };
    __shared__ __align__(16) SM sm;
    unsigned short* Ks = sm.a.Ks;
    unsigned short* Vt = sm.a.Vt;
    unsigned short* Ps = sm.a.Ps;

    const int bid  = blockIdx.x;
    const int qt   = 31 - (bid >> 5);       // 64-row q-tile, heavy-first
    const int bh   = bid & 31;
    const int b    = bh >> 4;
    const int h    = bh & 15;
    const int t    = threadIdx.x;
    const int lane = t & 63;
    const int w    = t >> 6;
    const int quad = lane >> 4;
    const int l16  = lane & 15;

    const int wrow0  = qt * 64 + w * 16;    // wave q-row base (16 rows)
    const int ntiles = qt + 1;              // K tiles of 64

    unsigned short* Pw = Ps + w * 16 * PSTR;

    // staging maps (256 threads)
    const int krow = t >> 2, kub = (t & 3) * 4;    // K: row, 16B-unit base
    const int vq   = t & 31, vd0 = (t >> 5) * 16;  // V: s-pair, d-block

    // Q A-fragments from global: k = c*32 + quad*8 + j
    bf16x8 qf[4];
    {
        const unsigned short* qp =
            qb + ((size_t)(bh * S_ + wrow0 + l16)) * HD_ + quad * 8;
        #pragma unroll
        for (int c = 0; c < 4; c++)
            qf[c] = *(const bf16x8*)(qp + c * 32);
    }

    f32x4 of[8];
    #pragma unroll
    for (int db = 0; db < 8; db++)
        #pragma unroll
        for (int r = 0; r < 4; r++) of[db][r] = 0.0f;
    float mr[4], lr[4];
    #pragma unroll
    for (int r = 0; r < 4; r++) { mr[r] = -1e30f; lr[r] = 0.0f; }

    // log2-domain softmax: scale' = (1/sqrt(128))*log2(e), mask' = -1e4*log2(e)
    const float scale2 = 0.12751744459892879f;
    const float mneg2  = -14426.950408889634f;

    // prefetch registers
    uint4 kr[4];
    uint4 v0a, v0b, v1a, v1b;

    auto issue_tile = [&](int kt2) {
        const int s2 = kt2 * 64;
        const unsigned short* kg = kb + ((size_t)(bh * S_ + s2 + krow)) * HD_ + kub * 8;
        #pragma unroll
        for (int u = 0; u < 4; u++) kr[u] = *(const uint4*)(kg + u * 8);
        const unsigned short* vg = vb + ((size_t)(bh * S_ + s2 + 2 * vq)) * HD_ + vd0;
        v0a = *(const uint4*)(vg);
        v0b = *(const uint4*)(vg + 8);
        v1a = *(const uint4*)(vg + HD_);
        v1b = *(const uint4*)(vg + HD_ + 8);
    };

    issue_tile(0);

    for (int kt = 0; kt < ntiles; kt++) {
        const int s0 = kt * 64;
        __syncthreads();                  // prior iter's LDS readers done
        // ---- K tile -> LDS (row-major, b128, XOR-swizzled 16B units)
        #pragma unroll
        for (int u = 0; u < 4; u++) {
            const int unit = (kub + u) ^ (krow & 7);
            *(uint4*)&Ks[krow * KSTR + unit * 8] = kr[u];
        }
        // ---- V tile -> LDS transposed: Vt[d][s], s-pairs packed as b32
        {
            unsigned int r0[8] = { v0a.x, v0a.y, v0a.z, v0a.w,
                                   v0b.x, v0b.y, v0b.z, v0b.w };
            unsigned int r1[8] = { v1a.x, v1a.y, v1a.z, v1a.w,
                                   v1b.x, v1b.y, v1b.z, v1b.w };
            #pragma unroll
            for (int j = 0; j < 16; j++) {
                const int u = j >> 1;
                unsigned int pk;
                if ((j & 1) == 0)
                    pk = (r0[u] & 0xffffu) | (r1[u] << 16);
                else
                    pk = (r0[u] >> 16) | (r1[u] & 0xffff0000u);
                *(unsigned int*)&Vt[(vd0 + j) * VSTR + 2 * vq] = pk;
            }
        }
        __syncthreads();

        if (kt + 1 < ntiles) issue_tile(kt + 1);

        // ---- S = Q K^T : 4 nb MFMAs (swizzled kf reads; row&7 == l16&7)
        f32x4 sf[4];
        #pragma unroll
        for (int nb = 0; nb < 4; nb++)
            #pragma unroll
            for (int r = 0; r < 4; r++) sf[nb][r] = 0.0f;
        #pragma unroll
        for (int c = 0; c < 4; c++) {
            #pragma unroll
            for (int nb = 0; nb < 4; nb++) {
                const int unit = (4 * c + quad) ^ (l16 & 7);
                bf16x8 kf = *(const bf16x8*)&Ks[(nb * 16 + l16) * KSTR + unit * 8];
                sf[nb] = __builtin_amdgcn_mfma_f32_16x16x32_bf16(
                    qf[c], kf, sf[nb], 0, 0, 0);
            }
        }

        // ---- scale + causal mask, log2 domain
        const bool need_mask = (s0 + 63 > wrow0);
        {
            const int qr0 = wrow0 + quad * 4;
            #pragma unroll
            for (int nb = 0; nb < 4; nb++) {
                const int kcol = s0 + nb * 16 + l16;
                #pragma unroll
                for (int r = 0; r < 4; r++) {
                    float s = sf[nb][r] * scale2;
                    if (need_mask && kcol > qr0 + r) s += mneg2;
                    sf[nb][r] = s;
                }
            }
        }

        // ---- online softmax (max reduce over 16-lane group; lr partials;
        //      rescale deferred when no row max grew)
        {
            float mt4[4];
            #pragma unroll
            for (int r = 0; r < 4; r++) {
                float mt = fmaxf(fmaxf(sf[0][r], sf[1][r]),
                                 fmaxf(sf[2][r], sf[3][r]));
                mt = fmaxf(mt, __shfl_xor(mt, 1));
                mt = fmaxf(mt, __shfl_xor(mt, 2));
                mt = fmaxf(mt, __shfl_xor(mt, 4));
                mt = fmaxf(mt, __shfl_xor(mt, 8));
                mt4[r] = mt;
            }
            const bool grew = (mt4[0] > mr[0]) || (mt4[1] > mr[1]) ||
                              (mt4[2] > mr[2]) || (mt4[3] > mr[3]);
            if (__any(grew)) {
                float alpha[4];
                #pragma unroll
                for (int r = 0; r < 4; r++) {
                    const float mnew = fmaxf(mr[r], mt4[r]);
                    alpha[r] = __builtin_amdgcn_exp2f(mr[r] - mnew);
                    mr[r] = mnew;
                    lr[r] *= alpha[r];
                }
                #pragma unroll
                for (int db = 0; db < 8; db++)
                    #pragma unroll
                    for (int r = 0; r < 4; r++) of[db][r] *= alpha[r];
            }
            #pragma unroll
            for (int r = 0; r < 4; r++) {
                float rs = 0.0f;
                #pragma unroll
                for (int nb = 0; nb < 4; nb++) {
                    float p = __builtin_amdgcn_exp2f(sf[nb][r] - mr[r]);
                    sf[nb][r] = p;
                    rs += p;
                }
                lr[r] += rs;       // per-lane partial; reduced in epilogue
            }

            // P: C-layout -> wave-private LDS [m][s]
            #pragma unroll
            for (int nb = 0; nb < 4; nb++)
                #pragma unroll
                for (int r = 0; r < 4; r++)
                    Pw[(quad * 4 + r) * PSTR + nb * 16 + l16] = f2b(sf[nb][r]);
        }

        // ---- O += P V
        #pragma unroll
        for (int kc = 0; kc < 2; kc++) {
            bf16x8 pf = *(const bf16x8*)&Pw[l16 * PSTR + kc * 32 + quad * 8];
            #pragma unroll
            for (int db = 0; db < 8; db++) {
                bf16x8 vf = *(const bf16x8*)&Vt[(db * 16 + l16) * VSTR + kc * 32 + quad * 8];
                of[db] = __builtin_amdgcn_mfma_f32_16x16x32_bf16(
                    pf, vf, of[db], 0, 0, 0);
            }
        }
    }

    // ---- epilogue: lane-reduce lr, normalize, LDS transpose, float4 stores.
    float* Ow = sm.Ow + w * 16 * OSTR;     // wave-private 16x132 fp32
    __syncthreads();                       // all readers of Ks/Vt/Ps done
    float inv[4];
    #pragma unroll
    for (int r = 0; r < 4; r++) {
        float ls = lr[r];
        ls += __shfl_xor(ls, 1);
        ls += __shfl_xor(ls, 2);
        ls += __shfl_xor(ls, 4);
        ls += __shfl_xor(ls, 8);
        inv[r] = 1.0f / ls;
    }
    #pragma unroll
    for (int db = 0; db < 8; db++)
        #pragma unroll
        for (int r = 0; r < 4; r++)
            Ow[(quad * 4 + r) * OSTR + db * 16 + l16] = of[db][r] * inv[r];
    #pragma unroll
    for (int rg = 0; rg < 4; rg++) {
        const int rowl = rg * 4 + quad;
        float* op = out + ((size_t)(b * S_ + wrow0 + rowl)) * E_ + h * HD_;
        #pragma unroll
        for (int u = 0; u < 2; u++) {
            float4 v4 = *(const float4*)&Ow[rowl * OSTR + u * 64 + l16 * 4];
            *(float4*)(op + u * 64 + l16 * 4) = v4;
        }
    }
}

// ---------------------------------------------------------------------------
extern "C" void kernel_launch(void* const* d_in, const int* in_sizes, int n_in,
                              void* d_out, int out_size, void* d_ws, size_t ws_size,
                              hipStream_t stream)
{
    const float* x    = (const float*)d_in[0];   // fp32 (B,S,E)
    const float* W    = (const float*)d_in[1];   // fp32 (6144,2048)
    const float* bias = (const float*)d_in[2];   // fp32 (6144,)
    float* out = (float*)d_out;                  // fp32 (B,S,E)

    const size_t per = (size_t)B_ * NH_ * S_ * HD_;               // 8388608
    unsigned short* qb = (unsigned short*)d_ws;                   // [B][NH][S][HD]
    unsigned short* kb = qb + per;                                // [B][NH][S][HD]
    unsigned short* vb = kb + per;                                // [B][NH][S][HD]
    unsigned short* Xb = vb + per;                                // bf16 X  (16.8 MB)
    unsigned short* Wb = Xb + (size_t)XN_;                        // bf16 W  (25.2 MB)

    const int cvt_elems = XN_ + NQKV_ * E_;                       // 20971520
    cvt_bf16<<<cvt_elems / (256 * 8), 256, 0, stream>>>(x, W, Xb);

    dim3 gemm_grid((M_ / 128) * (NQKV_ / 256));                   // 32*24 = 768
    qkv_gemm<<<gemm_grid, 512, 0, stream>>>(Xb, Wb, bias, qb, kb, vb);

    attn_mfma<<<dim3(32 * 32), 256, 0, stream>>>(qb, kb, vb, out);
}

// Round 8
// 345.383 us; speedup vs baseline: 1.3655x; 1.0672x over previous
//
#include <hip/hip_runtime.h>

// MHA: cvt fp32->bf16 -> QKV GEMM (128x256 pipelined, LDS-coalesced epilogue,
//      V stored transposed) -> MFMA flash attention (gload_lds K/V staging)
// B=2 S=2048 E=2048 NH=16 HD=128 ROTARY=32 base=1e4 NEG_INF=-1e4
#define B_    2
#define S_    2048
#define E_    2048
#define NH_   16
#define HD_   128
#define NQKV_ 6144
#define M_    4096
#define XN_   (M_ * E_)          // 8388608 X elements
#define NPAN  (E_ / 32)          // 64 K-panels of 32

typedef short bf16x8 __attribute__((ext_vector_type(8)));   // 8 bf16 (4 VGPRs)
typedef float f32x4  __attribute__((ext_vector_type(4)));   // MFMA C/D

typedef const __attribute__((address_space(1))) void* gas_t; // global addrspace
typedef __attribute__((address_space(3))) void*       las_t; // LDS addrspace

__device__ inline float b2f(unsigned short u) {
    return __uint_as_float(((unsigned int)u) << 16);
}
__device__ inline unsigned short f2b(float f) {             // RNE f32->bf16
    unsigned int x = __float_as_uint(f);
    x = x + 0x7fffu + ((x >> 16) & 1u);
    return (unsigned short)(x >> 16);
}
__device__ inline unsigned int pk2(float lo, float hi) {
    return (unsigned int)f2b(lo) | ((unsigned int)f2b(hi) << 16);
}

// ---------------------------------------------------------------------------
// Kernel 0: one-shot fp32 -> bf16 of X (8.39M) and W (12.58M) into workspace.
// ---------------------------------------------------------------------------
__global__ __launch_bounds__(256) void cvt_bf16(
    const float* __restrict__ X,
    const float* __restrict__ W,
    unsigned short* __restrict__ O)      // [XN_ of X][W follows]
{
    const long i = (long)(blockIdx.x * 256 + threadIdx.x) * 8;
    const float* src = (i < XN_) ? (X + i) : (W + (i - XN_));
    const float4 a = *(const float4*)(src);
    const float4 b = *(const float4*)(src + 4);
    uint4 o = { pk2(a.x, a.y), pk2(a.z, a.w), pk2(b.x, b.y), pk2(b.z, b.w) };
    *(uint4*)(O + i) = o;
}

// ---------------------------------------------------------------------------
// Kernel 1: QKV = Xb * Wb^T + bias, RoPE fused. Main loop = round-6 (3-slot,
// depth-2 gload_lds pipeline, measured-correct).
// ROUND-7 epilogue: LDS-staged COALESCED b128 stores (old: 64 scalar 2B
// scatter stores/thread -> sector RMW, WRITE_SIZE 53MB for 25MB output).
//  * q/k blocks: E[128][264] bf16 (m-major), re-read row-wise -> 16B stores
//    to qb/kb[bh][s][d].
//  * v blocks:  E[256][136] bf16 (col-major), re-read -> 16B stores to the
//    TRANSPOSED layout vt[bh][d][s]  (free transpose; attn consumes V
//    row-readable, eliminating its per-iter V-transpose pack).
// ---------------------------------------------------------------------------
__global__ __launch_bounds__(512, 4) void qkv_gemm(
    const unsigned short* __restrict__ Xb,   // bf16 [4096][2048]
    const unsigned short* __restrict__ Wb,   // bf16 [6144][2048]
    const float* __restrict__ bias,
    unsigned short* __restrict__ qb,
    unsigned short* __restrict__ kb,
    unsigned short* __restrict__ vt)         // bf16 [B][NH][HD][S]
{
    union GS {
        struct {
            unsigned short As[3][128 * 32];  // 24 KiB
            unsigned short Bs[3][256 * 32];  // 48 KiB
        } s;
        unsigned short Eqk[128 * 264];       // 67584 B (epilogue reuse)
        unsigned short Ev [256 * 136];       // 69632 B (epilogue reuse)
    };
    __shared__ __align__(16) GS gs;

    const int t    = threadIdx.x;            // 0..511
    const int lane = t & 63;
    const int w    = t >> 6;                 // 0..7
    const int wr   = w >> 2;                 // 0..1  (m half, 64 rows)
    const int wc   = w & 3;                  // 0..3  (n quarter, 64 cols)
    const int quad = (lane >> 4) & 3;
    const int l16  = lane & 15;

    // XCD-aware bijective swizzle: 768 = 8 * 96
    const int wg = ((int)blockIdx.x & 7) * 96 + ((int)blockIdx.x >> 3);
    const int m0 = (wg / 24) * 128;          // 0..31 -> 128-row tiles
    const int n0 = (wg % 24) * 256;          // 0..23 -> 256-col tiles

    auto stageA = [&](int p) {
        const int sl = p % 3;
        const int k0 = p * 32;
        const int ub  = w * 64;
        const int u   = ub + lane;
        const int row = u >> 2;
        const int ko  = (u & 3) ^ ((row >> 1) & 3);
        __builtin_amdgcn_global_load_lds(
            (gas_t)(Xb + (size_t)(m0 + row) * E_ + k0 + ko * 8),
            (las_t)&gs.s.As[sl][ub * 8], 16, 0, 0);
    };
    auto stageB = [&](int p) {
        const int sl = p % 3;
        const int k0 = p * 32;
        #pragma unroll
        for (int c = 0; c < 2; c++) {
            const int ub  = c * 512 + w * 64;
            const int u   = ub + lane;
            const int row = u >> 2;
            const int ko  = (u & 3) ^ ((row >> 1) & 3);
            __builtin_amdgcn_global_load_lds(
                (gas_t)(Wb + (size_t)(n0 + row) * E_ + k0 + ko * 8),
                (las_t)&gs.s.Bs[sl][ub * 8], 16, 0, 0);
        }
    };

    f32x4 acc[4][4];
    #pragma unroll
    for (int i = 0; i < 4; i++)
        #pragma unroll
        for (int j = 0; j < 4; j++)
            #pragma unroll
            for (int r = 0; r < 4; r++) acc[i][j][r] = 0.0f;

    stageA(0); stageB(0);
    stageA(1); stageB(1);
    asm volatile("s_waitcnt vmcnt(0)" ::: "memory");
    __builtin_amdgcn_s_barrier();

    for (int p = 0; p < NPAN; p++) {
        const int sl = p % 3;
        bf16x8 af[4], bfv[4];

        #pragma unroll
        for (int mf = 0; mf < 4; mf++) {
            const int row = wr * 64 + mf * 16 + l16;
            af[mf] = *(const bf16x8*)&gs.s.As[sl][row * 32 + (quad ^ ((row >> 1) & 3)) * 8];
        }
        #pragma unroll
        for (int nf = 0; nf < 4; nf++) {
            const int rb = wc * 64 + nf * 16 + l16;
            bfv[nf] = *(const bf16x8*)&gs.s.Bs[sl][rb * 32 + (quad ^ ((rb >> 1) & 3)) * 8];
        }

        if (p + 2 < NPAN) {
            stageA(p + 2); stageB(p + 2);
            asm volatile("s_waitcnt vmcnt(3)" ::: "memory");   // p+1 landed
        } else {
            asm volatile("s_waitcnt vmcnt(0)" ::: "memory");   // tail
        }
        __builtin_amdgcn_s_barrier();
        __builtin_amdgcn_s_setprio(1);
        #pragma unroll
        for (int mf = 0; mf < 4; mf++)
            #pragma unroll
            for (int nf = 0; nf < 4; nf++)
                acc[mf][nf] = __builtin_amdgcn_mfma_f32_16x16x32_bf16(
                    af[mf], bfv[nf], acc[mf][nf], 0, 0, 0);
        __builtin_amdgcn_s_setprio(0);
        __builtin_amdgcn_s_barrier();
    }

    // ---- bias + fused RoPE on registers
    const int which = n0 >> 11;                   // 0=q 1=k 2=v (const/block)

    float bv[4];
    #pragma unroll
    for (int nf = 0; nf < 4; nf++) bv[nf] = bias[n0 + wc * 64 + nf * 16 + l16];
    #pragma unroll
    for (int mi = 0; mi < 4; mi++)
        #pragma unroll
        for (int nf = 0; nf < 4; nf++)
            #pragma unroll
            for (int r = 0; r < 4; r++) acc[mi][nf][r] += bv[nf];

    // RoPE: tile spans 2 heads; head-local d<64 quarters are wc==0 / wc==2.
    if ((wc & 1) == 0 && which < 2) {
        const float inv = exp2f(-0.83048202372184059f * (float)l16); // 1e4^(-d/16)
        #pragma unroll
        for (int mi = 0; mi < 4; mi++) {
            #pragma unroll
            for (int r = 0; r < 4; r++) {
                const int m = m0 + wr * 64 + mi * 16 + quad * 4 + r;
                const int sdx = m & (S_ - 1);
                float c, sn;
                __sincosf((float)sdx * inv, &sn, &c);
                const float u1 = acc[mi][0][r], u2 = acc[mi][1][r];
                acc[mi][0][r] = u1 * c - u2 * sn;
                acc[mi][1][r] = u1 * sn + u2 * c;
            }
        }
    }

    // ---- LDS-staged coalesced stores (main loop's final barrier passed;
    // all As/Bs reads retired -> union reuse safe).
    const int hb = (n0 >> 7) & 15;                // head base of this tile
    const int bb = m0 >> 11;
    const int sb = m0 & (S_ - 1);
    if (which < 2) {
        unsigned short* dst = (which == 0) ? qb : kb;
        unsigned short* E = gs.Eqk;               // [128][264]
        #pragma unroll
        for (int mi = 0; mi < 4; mi++) {
            const int m = wr * 64 + mi * 16 + quad * 4;
            #pragma unroll
            for (int nf = 0; nf < 4; nf++) {
                const int col = wc * 64 + nf * 16 + l16;
                #pragma unroll
                for (int r = 0; r < 4; r++)
                    E[(m + r) * 264 + col] = f2b(acc[mi][nf][r]);
            }
        }
        __syncthreads();
        const int em  = t >> 2;                   // 0..127
        const int ecg = (t & 3) * 8;              // chunk base
        unsigned short* orow =
            dst + ((size_t)(bb * NH_ + hb) * S_ + sb + em) * HD_;
        #pragma unroll
        for (int i = 0; i < 8; i++) {
            const int chunk = ecg + i;            // 0..31
            const int hh = chunk >> 4;            // +0/1 within tile
            const int d  = (chunk & 15) * 8;
            uint4 vv = *(const uint4*)&E[em * 264 + chunk * 8];
            *(uint4*)&orow[(size_t)hh * (HD_ * S_) + d] = vv;
        }
    } else {
        unsigned short* E = gs.Ev;                // [256][136]
        #pragma unroll
        for (int mi = 0; mi < 4; mi++) {
            const int m = wr * 64 + mi * 16 + quad * 4;
            #pragma unroll
            for (int nf = 0; nf < 4; nf++) {
                const int col = wc * 64 + nf * 16 + l16;
                #pragma unroll
                for (int r = 0; r < 4; r++)
                    E[col * 136 + m + r] = f2b(acc[mi][nf][r]);
            }
        }
        __syncthreads();
        const int col = t >> 1;                   // 0..255
        const int cb  = (t & 1) * 8;              // chunk base 0/8
        const int hh  = hb + (col >> 7);
        const int d   = col & 127;
        unsigned short* vrow =
            vt + ((size_t)(bb * NH_ + hh) * HD_ + d) * S_ + sb;
        #pragma unroll
        for (int i = 0; i < 8; i++) {
            const int chunk = cb + i;             // 0..15
            uint4 vv = *(const uint4*)&E[col * 136 + chunk * 8];
            *(uint4*)&vrow[chunk * 8] = vv;
        }
    }
}

// ---------------------------------------------------------------------------
// Kernel 2: MFMA causal flash attention. ROUND-7 restructure:
//  * V comes from vt[bh][d][s]: no per-iter transpose pack (was 4 uint4
//    loads + ~33 VALU + 16 ds_write_b32 per thread per iter on the serial
//    critical path -> the measured 26.5% VALUBusy / 10% MfmaUtil).
//  * K and V staged via global_load_lds (zero VALU, zero explicit LDS
//    writes), double-buffered, ONE __syncthreads per iter: stage(t+1)
//    issued at iter top, drained by iter-end syncthreads (vmcnt0) after a
//    full compute phase -> latency hidden.
//  * Both-sides XOR swizzle (rule 21): source chunk = unit ^ (row&7)
//    pre-applied on the per-lane GLOBAL address (gload_lds writes LDS
//    linearly), ds_read uses unit' = logical ^ (l16&7). Bank check: 8
//    distinct 16B-unit groups x (l16,l16+8) pairs = 2 lanes/bank = free.
// LDS: Ks 2x[64][128] + Vs 2x[128][64] + Ps = 74752 B -> 2 blocks/CU.
// Layouts (HW-verified 16x16x32_bf16): A[m=lane&15][k=quad*8+j];
// C/D row=quad*4+reg, col=lane&15.
// ---------------------------------------------------------------------------
#define PSTR 72
#define OSTR 132

__global__ __launch_bounds__(256, 2) void attn_mfma(
    const unsigned short* __restrict__ qb,
    const unsigned short* __restrict__ kb,
    const unsigned short* __restrict__ vt,
    float* __restrict__ out)
{
    union SM {
        struct {
            unsigned short Ks[2][64 * 128];    // 32768 B
            unsigned short Vs[2][128 * 64];    // 32768 B
            unsigned short Ps[4 * 16 * PSTR];  //  9216 B
        } a;                                   // 74752 B total
        float Ow[4 * 16 * OSTR];               // 33792 B (epilogue reuse)
    };
    __shared__ __align__(16) SM sm;

    const int bid  = blockIdx.x;
    const int qt   = 31 - (bid >> 5);       // 64-row q-tile, heavy-first
    const int bh   = bid & 31;
    const int b    = bh >> 4;
    const int h    = bh & 15;
    const int t    = threadIdx.x;
    const int lane = t & 63;
    const int w    = t >> 6;
    const int quad = lane >> 4;
    const int l16  = lane & 15;

    const int wrow0  = qt * 64 + w * 16;    // wave q-row base (16 rows)
    const int ntiles = qt + 1;              // K tiles of 64

    unsigned short* Pw = sm.a.Ps + w * 16 * PSTR;

    // staging lane maps: K rows = s (256B each, 16 lanes); V rows = d (128B, 8)
    const int ksrow = w * 4 + (lane >> 4);  // + c*16
    const int ksu   = lane & 15;
    const int vdrow = w * 8 + (lane >> 3);  // + c*32
    const int vsu   = lane & 7;

    auto stage = [&](int kt2, int bsel) {
        const int s2 = kt2 * 64;
        #pragma unroll
        for (int c = 0; c < 4; c++) {
            const int srow = c * 16 + ksrow;
            __builtin_amdgcn_global_load_lds(
                (gas_t)(kb + ((size_t)(bh * S_ + s2 + srow)) * HD_
                        + (ksu ^ (srow & 7)) * 8),
                (las_t)&sm.a.Ks[bsel][(c * 16 + w * 4) * 128], 16, 0, 0);
        }
        #pragma unroll
        for (int c = 0; c < 4; c++) {
            const int drow = c * 32 + vdrow;
            __builtin_amdgcn_global_load_lds(
                (gas_t)(vt + ((size_t)(bh * HD_ + drow)) * S_ + s2
                        + (vsu ^ (drow & 7)) * 8),
                (las_t)&sm.a.Vs[bsel][(c * 32 + w * 8) * 64], 16, 0, 0);
        }
    };

    // Q A-fragments from global: k = c*32 + quad*8 + j
    bf16x8 qf[4];
    {
        const unsigned short* qp =
            qb + ((size_t)(bh * S_ + wrow0 + l16)) * HD_ + quad * 8;
        #pragma unroll
        for (int c = 0; c < 4; c++)
            qf[c] = *(const bf16x8*)(qp + c * 32);
    }

    f32x4 of[8];
    #pragma unroll
    for (int db = 0; db < 8; db++)
        #pragma unroll
        for (int r = 0; r < 4; r++) of[db][r] = 0.0f;
    float mr[4], lr[4];
    #pragma unroll
    for (int r = 0; r < 4; r++) { mr[r] = -1e30f; lr[r] = 0.0f; }

    // log2-domain softmax: scale' = (1/sqrt(128))*log2(e), mask' = -1e4*log2(e)
    const float scale2 = 0.12751744459892879f;
    const float mneg2  = -14426.950408889634f;

    stage(0, 0);
    __syncthreads();                 // vmcnt(0) + barrier: tile 0 landed
    int cur = 0;

    for (int kt = 0; kt < ntiles; kt++) {
        const int s0 = kt * 64;
        if (kt + 1 < ntiles) stage(kt + 1, cur ^ 1);   // hidden under compute

        // ---- S = Q K^T (swizzled kf reads)
        f32x4 sf[4];
        #pragma unroll
        for (int nb = 0; nb < 4; nb++)
            #pragma unroll
            for (int r = 0; r < 4; r++) sf[nb][r] = 0.0f;
        #pragma unroll
        for (int c = 0; c < 4; c++) {
            #pragma unroll
            for (int nb = 0; nb < 4; nb++) {
                const int u = (c * 4 + quad) ^ (l16 & 7);
                bf16x8 kf = *(const bf16x8*)
                    &sm.a.Ks[cur][(nb * 16 + l16) * 128 + u * 8];
                sf[nb] = __builtin_amdgcn_mfma_f32_16x16x32_bf16(
                    qf[c], kf, sf[nb], 0, 0, 0);
            }
        }

        // ---- scale + causal mask, log2 domain
        const bool need_mask = (s0 + 63 > wrow0);
        {
            const int qr0 = wrow0 + quad * 4;
            #pragma unroll
            for (int nb = 0; nb < 4; nb++) {
                const int kcol = s0 + nb * 16 + l16;
                #pragma unroll
                for (int r = 0; r < 4; r++) {
                    float s = sf[nb][r] * scale2;
                    if (need_mask && kcol > qr0 + r) s += mneg2;
                    sf[nb][r] = s;
                }
            }
        }

        // ---- online softmax (16-lane max reduce; lr partials; deferred
        //      rescale when no row max grew)
        {
            float mt4[4];
            #pragma unroll
            for (int r = 0; r < 4; r++) {
                float mt = fmaxf(fmaxf(sf[0][r], sf[1][r]),
                                 fmaxf(sf[2][r], sf[3][r]));
                mt = fmaxf(mt, __shfl_xor(mt, 1));
                mt = fmaxf(mt, __shfl_xor(mt, 2));
                mt = fmaxf(mt, __shfl_xor(mt, 4));
                mt = fmaxf(mt, __shfl_xor(mt, 8));
                mt4[r] = mt;
            }
            const bool grew = (mt4[0] > mr[0]) || (mt4[1] > mr[1]) ||
                              (mt4[2] > mr[2]) || (mt4[3] > mr[3]);
            if (__any(grew)) {
                float alpha[4];
                #pragma unroll
                for (int r = 0; r < 4; r++) {
                    const float mnew = fmaxf(mr[r], mt4[r]);
                    alpha[r] = __builtin_amdgcn_exp2f(mr[r] - mnew);
                    mr[r] = mnew;
                    lr[r] *= alpha[r];
                }
                #pragma unroll
                for (int db = 0; db < 8; db++)
                    #pragma unroll
                    for (int r = 0; r < 4; r++) of[db][r] *= alpha[r];
            }
            #pragma unroll
            for (int r = 0; r < 4; r++) {
                float rs = 0.0f;
                #pragma unroll
                for (int nb = 0; nb < 4; nb++) {
                    float p = __builtin_amdgcn_exp2f(sf[nb][r] - mr[r]);
                    sf[nb][r] = p;
                    rs += p;
                }
                lr[r] += rs;       // per-lane partial; reduced in epilogue
            }

            // P: C-layout -> wave-private LDS [m][s]
            #pragma unroll
            for (int nb = 0; nb < 4; nb++)
                #pragma unroll
                for (int r = 0; r < 4; r++)
                    Pw[(quad * 4 + r) * PSTR + nb * 16 + l16] = f2b(sf[nb][r]);
        }

        // ---- O += P V (swizzled vf reads from row-readable Vs[d][s])
        #pragma unroll
        for (int kc = 0; kc < 2; kc++) {
            bf16x8 pf = *(const bf16x8*)&Pw[l16 * PSTR + kc * 32 + quad * 8];
            #pragma unroll
            for (int db = 0; db < 8; db++) {
                const int u = (kc * 4 + quad) ^ (l16 & 7);
                bf16x8 vf = *(const bf16x8*)
                    &sm.a.Vs[cur][(db * 16 + l16) * 64 + u * 8];
                of[db] = __builtin_amdgcn_mfma_f32_16x16x32_bf16(
                    pf, vf, of[db], 0, 0, 0);
            }
        }

        __syncthreads();           // drains my stage(t+1) + all waves done
        cur ^= 1;
    }

    // ---- epilogue: lane-reduce lr, normalize, LDS transpose, float4 stores.
    float* Ow = sm.Ow + w * 16 * OSTR;     // wave-private 16x132 fp32
    float inv[4];
    #pragma unroll
    for (int r = 0; r < 4; r++) {
        float ls = lr[r];
        ls += __shfl_xor(ls, 1);
        ls += __shfl_xor(ls, 2);
        ls += __shfl_xor(ls, 4);
        ls += __shfl_xor(ls, 8);
        inv[r] = 1.0f / ls;
    }
    #pragma unroll
    for (int db = 0; db < 8; db++)
        #pragma unroll
        for (int r = 0; r < 4; r++)
            Ow[(quad * 4 + r) * OSTR + db * 16 + l16] = of[db][r] * inv[r];
    #pragma unroll
    for (int rg = 0; rg < 4; rg++) {
        const int rowl = rg * 4 + quad;
        float* op = out + ((size_t)(b * S_ + wrow0 + rowl)) * E_ + h * HD_;
        #pragma unroll
        for (int u = 0; u < 2; u++) {
            float4 v4 = *(const float4*)&Ow[rowl * OSTR + u * 64 + l16 * 4];
            *(float4*)(op + u * 64 + l16 * 4) = v4;
        }
    }
}

// ---------------------------------------------------------------------------
extern "C" void kernel_launch(void* const* d_in, const int* in_sizes, int n_in,
                              void* d_out, int out_size, void* d_ws, size_t ws_size,
                              hipStream_t stream)
{
    const float* x    = (const float*)d_in[0];   // fp32 (B,S,E)
    const float* W    = (const float*)d_in[1];   // fp32 (6144,2048)
    const float* bias = (const float*)d_in[2];   // fp32 (6144,)
    float* out = (float*)d_out;                  // fp32 (B,S,E)

    const size_t per = (size_t)B_ * NH_ * S_ * HD_;               // 8388608
    unsigned short* qb = (unsigned short*)d_ws;                   // [B][NH][S][HD]
    unsigned short* kb = qb + per;                                // [B][NH][S][HD]
    unsigned short* vt = kb + per;                                // [B][NH][HD][S]
    unsigned short* Xb = vt + per;                                // bf16 X
    unsigned short* Wb = Xb + (size_t)XN_;                        // bf16 W

    const int cvt_elems = XN_ + NQKV_ * E_;                       // 20971520
    cvt_bf16<<<cvt_elems / (256 * 8), 256, 0, stream>>>(x, W, Xb);

    dim3 gemm_grid((M_ / 128) * (NQKV_ / 256));                   // 32*24 = 768
    qkv_gemm<<<gemm_grid, 512, 0, stream>>>(Xb, Wb, bias, qb, kb, vt);

    attn_mfma<<<dim3(32 * 32), 256, 0, stream>>>(qb, kb, vt, out);
}

// Round 9
// 317.964 us; speedup vs baseline: 1.4833x; 1.0862x over previous
//
#include <hip/hip_runtime.h>

// MHA: cvt fp32->bf16 -> QKV GEMM (128x256 pipelined, LDS-coalesced epilogue,
//      V stored transposed) -> MFMA flash attention (gload_lds K/V staging)
// B=2 S=2048 E=2048 NH=16 HD=128 ROTARY=32 base=1e4 NEG_INF=-1e4
#define B_    2
#define S_    2048
#define E_    2048
#define NH_   16
#define HD_   128
#define NQKV_ 6144
#define M_    4096
#define XN_   (M_ * E_)          // 8388608 X elements
#define NPAN  (E_ / 32)          // 64 K-panels of 32

typedef short bf16x8 __attribute__((ext_vector_type(8)));   // 8 bf16 (4 VGPRs)
typedef float f32x4  __attribute__((ext_vector_type(4)));   // MFMA C/D

typedef const __attribute__((address_space(1))) void* gas_t; // global addrspace
typedef __attribute__((address_space(3))) void*       las_t; // LDS addrspace

__device__ inline float b2f(unsigned short u) {
    return __uint_as_float(((unsigned int)u) << 16);
}
__device__ inline unsigned short f2b(float f) {             // RNE f32->bf16
    unsigned int x = __float_as_uint(f);
    x = x + 0x7fffu + ((x >> 16) & 1u);
    return (unsigned short)(x >> 16);
}
__device__ inline unsigned int pk2(float lo, float hi) {
    return (unsigned int)f2b(lo) | ((unsigned int)f2b(hi) << 16);
}

// ---------------------------------------------------------------------------
// Kernel 0: one-shot fp32 -> bf16 of X (8.39M) and W (12.58M) into workspace.
// ---------------------------------------------------------------------------
__global__ __launch_bounds__(256) void cvt_bf16(
    const float* __restrict__ X,
    const float* __restrict__ W,
    unsigned short* __restrict__ O)      // [XN_ of X][W follows]
{
    const long i = (long)(blockIdx.x * 256 + threadIdx.x) * 8;
    const float* src = (i < XN_) ? (X + i) : (W + (i - XN_));
    const float4 a = *(const float4*)(src);
    const float4 b = *(const float4*)(src + 4);
    uint4 o = { pk2(a.x, a.y), pk2(a.z, a.w), pk2(b.x, b.y), pk2(b.z, b.w) };
    *(uint4*)(O + i) = o;
}

// ---------------------------------------------------------------------------
// Kernel 1: QKV = Xb * Wb^T + bias, RoPE fused. Main loop = round-6 (3-slot,
// depth-2 gload_lds pipeline), LDS-coalesced epilogue (round-7).
// ROUND-8: XCD swizzle fixed for L2 residency. Round-7 mapping gave each XCD
// 4 m-tiles x ALL 24 n-tiles -> resident generation streamed ~24MB of W
// (>> 4MB L2) -> measured FETCH 310MB (theory: 1.5 gen x 25MB x 8 = 300MB).
// New mapping: XCD x owns a 3-wide n-slab (3 x 1MB of W = 3MB, L2-RESIDENT)
// and streams m: n = 3x + j%3, m = j/3. Per-XCD fetch ~= W-slab once (3.2MB)
// + X stream (16.8MB, L3-shared) -> predicted FETCH ~130-170MB and staging
// served from L2 (~200cyc) instead of HBM (~900cyc).
// ---------------------------------------------------------------------------
__global__ __launch_bounds__(512, 4) void qkv_gemm(
    const unsigned short* __restrict__ Xb,   // bf16 [4096][2048]
    const unsigned short* __restrict__ Wb,   // bf16 [6144][2048]
    const float* __restrict__ bias,
    unsigned short* __restrict__ qb,
    unsigned short* __restrict__ kb,
    unsigned short* __restrict__ vt)         // bf16 [B][NH][HD][S]
{
    union GS {
        struct {
            unsigned short As[3][128 * 32];  // 24 KiB
            unsigned short Bs[3][256 * 32];  // 48 KiB
        } s;
        unsigned short Eqk[128 * 264];       // 67584 B (epilogue reuse)
        unsigned short Ev [256 * 136];       // 69632 B (epilogue reuse)
    };
    __shared__ __align__(16) GS gs;

    const int t    = threadIdx.x;            // 0..511
    const int lane = t & 63;
    const int w    = t >> 6;                 // 0..7
    const int wr   = w >> 2;                 // 0..1  (m half, 64 rows)
    const int wc   = w & 3;                  // 0..3  (n quarter, 64 cols)
    const int quad = (lane >> 4) & 3;
    const int l16  = lane & 15;

    // XCD-aware 2D-locality swizzle (bid&7 = XCD, 768 = 8 * 96):
    // XCD x -> n-slab {3x..3x+2} (W slab 3MB, L2-resident), m streamed.
    const int xcd = (int)blockIdx.x & 7;
    const int j   = (int)blockIdx.x >> 3;    // 0..95
    const int m0  = (j / 3) * 128;           // 0..31 -> 128-row tiles
    const int n0  = (xcd * 3 + (j % 3)) * 256; // 0..23 -> 256-col tiles

    auto stageA = [&](int p) {
        const int sl = p % 3;
        const int k0 = p * 32;
        const int ub  = w * 64;
        const int u   = ub + lane;
        const int row = u >> 2;
        const int ko  = (u & 3) ^ ((row >> 1) & 3);
        __builtin_amdgcn_global_load_lds(
            (gas_t)(Xb + (size_t)(m0 + row) * E_ + k0 + ko * 8),
            (las_t)&gs.s.As[sl][ub * 8], 16, 0, 0);
    };
    auto stageB = [&](int p) {
        const int sl = p % 3;
        const int k0 = p * 32;
        #pragma unroll
        for (int c = 0; c < 2; c++) {
            const int ub  = c * 512 + w * 64;
            const int u   = ub + lane;
            const int row = u >> 2;
            const int ko  = (u & 3) ^ ((row >> 1) & 3);
            __builtin_amdgcn_global_load_lds(
                (gas_t)(Wb + (size_t)(n0 + row) * E_ + k0 + ko * 8),
                (las_t)&gs.s.Bs[sl][ub * 8], 16, 0, 0);
        }
    };

    f32x4 acc[4][4];
    #pragma unroll
    for (int i = 0; i < 4; i++)
        #pragma unroll
        for (int j2 = 0; j2 < 4; j2++)
            #pragma unroll
            for (int r = 0; r < 4; r++) acc[i][j2][r] = 0.0f;

    stageA(0); stageB(0);
    stageA(1); stageB(1);
    asm volatile("s_waitcnt vmcnt(0)" ::: "memory");
    __builtin_amdgcn_s_barrier();

    for (int p = 0; p < NPAN; p++) {
        const int sl = p % 3;
        bf16x8 af[4], bfv[4];

        #pragma unroll
        for (int mf = 0; mf < 4; mf++) {
            const int row = wr * 64 + mf * 16 + l16;
            af[mf] = *(const bf16x8*)&gs.s.As[sl][row * 32 + (quad ^ ((row >> 1) & 3)) * 8];
        }
        #pragma unroll
        for (int nf = 0; nf < 4; nf++) {
            const int rb = wc * 64 + nf * 16 + l16;
            bfv[nf] = *(const bf16x8*)&gs.s.Bs[sl][rb * 32 + (quad ^ ((rb >> 1) & 3)) * 8];
        }

        if (p + 2 < NPAN) {
            stageA(p + 2); stageB(p + 2);
            asm volatile("s_waitcnt vmcnt(3)" ::: "memory");   // p+1 landed
        } else {
            asm volatile("s_waitcnt vmcnt(0)" ::: "memory");   // tail
        }
        __builtin_amdgcn_s_barrier();
        __builtin_amdgcn_s_setprio(1);
        #pragma unroll
        for (int mf = 0; mf < 4; mf++)
            #pragma unroll
            for (int nf = 0; nf < 4; nf++)
                acc[mf][nf] = __builtin_amdgcn_mfma_f32_16x16x32_bf16(
                    af[mf], bfv[nf], acc[mf][nf], 0, 0, 0);
        __builtin_amdgcn_s_setprio(0);
        __builtin_amdgcn_s_barrier();
    }

    // ---- bias + fused RoPE on registers
    const int which = n0 >> 11;                   // 0=q 1=k 2=v (const/block)

    float bv[4];
    #pragma unroll
    for (int nf = 0; nf < 4; nf++) bv[nf] = bias[n0 + wc * 64 + nf * 16 + l16];
    #pragma unroll
    for (int mi = 0; mi < 4; mi++)
        #pragma unroll
        for (int nf = 0; nf < 4; nf++)
            #pragma unroll
            for (int r = 0; r < 4; r++) acc[mi][nf][r] += bv[nf];

    // RoPE: tile spans 2 heads; head-local d<64 quarters are wc==0 / wc==2.
    if ((wc & 1) == 0 && which < 2) {
        const float inv = exp2f(-0.83048202372184059f * (float)l16); // 1e4^(-d/16)
        #pragma unroll
        for (int mi = 0; mi < 4; mi++) {
            #pragma unroll
            for (int r = 0; r < 4; r++) {
                const int m = m0 + wr * 64 + mi * 16 + quad * 4 + r;
                const int sdx = m & (S_ - 1);
                float c, sn;
                __sincosf((float)sdx * inv, &sn, &c);
                const float u1 = acc[mi][0][r], u2 = acc[mi][1][r];
                acc[mi][0][r] = u1 * c - u2 * sn;
                acc[mi][1][r] = u1 * sn + u2 * c;
            }
        }
    }

    // ---- LDS-staged coalesced stores (main loop's final barrier passed;
    // all As/Bs reads retired -> union reuse safe).
    const int hb = (n0 >> 7) & 15;                // head base of this tile
    const int bb = m0 >> 11;
    const int sb = m0 & (S_ - 1);
    if (which < 2) {
        unsigned short* dst = (which == 0) ? qb : kb;
        unsigned short* E = gs.Eqk;               // [128][264]
        #pragma unroll
        for (int mi = 0; mi < 4; mi++) {
            const int m = wr * 64 + mi * 16 + quad * 4;
            #pragma unroll
            for (int nf = 0; nf < 4; nf++) {
                const int col = wc * 64 + nf * 16 + l16;
                #pragma unroll
                for (int r = 0; r < 4; r++)
                    E[(m + r) * 264 + col] = f2b(acc[mi][nf][r]);
            }
        }
        __syncthreads();
        const int em  = t >> 2;                   // 0..127
        const int ecg = (t & 3) * 8;              // chunk base
        unsigned short* orow =
            dst + ((size_t)(bb * NH_ + hb) * S_ + sb + em) * HD_;
        #pragma unroll
        for (int i = 0; i < 8; i++) {
            const int chunk = ecg + i;            // 0..31
            const int hh = chunk >> 4;            // +0/1 within tile
            const int d  = (chunk & 15) * 8;
            uint4 vv = *(const uint4*)&E[em * 264 + chunk * 8];
            *(uint4*)&orow[(size_t)hh * (HD_ * S_) + d] = vv;
        }
    } else {
        unsigned short* E = gs.Ev;                // [256][136]
        #pragma unroll
        for (int mi = 0; mi < 4; mi++) {
            const int m = wr * 64 + mi * 16 + quad * 4;
            #pragma unroll
            for (int nf = 0; nf < 4; nf++) {
                const int col = wc * 64 + nf * 16 + l16;
                #pragma unroll
                for (int r = 0; r < 4; r++)
                    E[col * 136 + m + r] = f2b(acc[mi][nf][r]);
            }
        }
        __syncthreads();
        const int col = t >> 1;                   // 0..255
        const int cb  = (t & 1) * 8;              // chunk base 0/8
        const int hh  = hb + (col >> 7);
        const int d   = col & 127;
        unsigned short* vrow =
            vt + ((size_t)(bb * NH_ + hh) * HD_ + d) * S_ + sb;
        #pragma unroll
        for (int i = 0; i < 8; i++) {
            const int chunk = cb + i;             // 0..15
            uint4 vv = *(const uint4*)&E[col * 136 + chunk * 8];
            *(uint4*)&vrow[chunk * 8] = vv;
        }
    }
}

// ---------------------------------------------------------------------------
// Kernel 2: MFMA causal flash attention (unchanged from round 7 — passing,
// fell out of top-5). V from vt[bh][d][s]; K/V staged via global_load_lds,
// double-buffered, one __syncthreads per iter; both-sides XOR swizzle.
// Layouts (HW-verified 16x16x32_bf16): A[m=lane&15][k=quad*8+j];
// C/D row=quad*4+reg, col=lane&15.
// ---------------------------------------------------------------------------
#define PSTR 72
#define OSTR 132

__global__ __launch_bounds__(256, 2) void attn_mfma(
    const unsigned short* __restrict__ qb,
    const unsigned short* __restrict__ kb,
    const unsigned short* __restrict__ vt,
    float* __restrict__ out)
{
    union SM {
        struct {
            unsigned short Ks[2][64 * 128];    // 32768 B
            unsigned short Vs[2][128 * 64];    // 32768 B
            unsigned short Ps[4 * 16 * PSTR];  //  9216 B
        } a;                                   // 74752 B total
        float Ow[4 * 16 * OSTR];               // 33792 B (epilogue reuse)
    };
    __shared__ __align__(16) SM sm;

    const int bid  = blockIdx.x;
    const int qt   = 31 - (bid >> 5);       // 64-row q-tile, heavy-first
    const int bh   = bid & 31;
    const int b    = bh >> 4;
    const int h    = bh & 15;
    const int t    = threadIdx.x;
    const int lane = t & 63;
    const int w    = t >> 6;
    const int quad = lane >> 4;
    const int l16  = lane & 15;

    const int wrow0  = qt * 64 + w * 16;    // wave q-row base (16 rows)
    const int ntiles = qt + 1;              // K tiles of 64

    unsigned short* Pw = sm.a.Ps + w * 16 * PSTR;

    // staging lane maps: K rows = s (256B each, 16 lanes); V rows = d (128B, 8)
    const int ksrow = w * 4 + (lane >> 4);  // + c*16
    const int ksu   = lane & 15;
    const int vdrow = w * 8 + (lane >> 3);  // + c*32
    const int vsu   = lane & 7;

    auto stage = [&](int kt2, int bsel) {
        const int s2 = kt2 * 64;
        #pragma unroll
        for (int c = 0; c < 4; c++) {
            const int srow = c * 16 + ksrow;
            __builtin_amdgcn_global_load_lds(
                (gas_t)(kb + ((size_t)(bh * S_ + s2 + srow)) * HD_
                        + (ksu ^ (srow & 7)) * 8),
                (las_t)&sm.a.Ks[bsel][(c * 16 + w * 4) * 128], 16, 0, 0);
        }
        #pragma unroll
        for (int c = 0; c < 4; c++) {
            const int drow = c * 32 + vdrow;
            __builtin_amdgcn_global_load_lds(
                (gas_t)(vt + ((size_t)(bh * HD_ + drow)) * S_ + s2
                        + (vsu ^ (drow & 7)) * 8),
                (las_t)&sm.a.Vs[bsel][(c * 32 + w * 8) * 64], 16, 0, 0);
        }
    };

    // Q A-fragments from global: k = c*32 + quad*8 + j
    bf16x8 qf[4];
    {
        const unsigned short* qp =
            qb + ((size_t)(bh * S_ + wrow0 + l16)) * HD_ + quad * 8;
        #pragma unroll
        for (int c = 0; c < 4; c++)
            qf[c] = *(const bf16x8*)(qp + c * 32);
    }

    f32x4 of[8];
    #pragma unroll
    for (int db = 0; db < 8; db++)
        #pragma unroll
        for (int r = 0; r < 4; r++) of[db][r] = 0.0f;
    float mr[4], lr[4];
    #pragma unroll
    for (int r = 0; r < 4; r++) { mr[r] = -1e30f; lr[r] = 0.0f; }

    // log2-domain softmax: scale' = (1/sqrt(128))*log2(e), mask' = -1e4*log2(e)
    const float scale2 = 0.12751744459892879f;
    const float mneg2  = -14426.950408889634f;

    stage(0, 0);
    __syncthreads();                 // vmcnt(0) + barrier: tile 0 landed
    int cur = 0;

    for (int kt = 0; kt < ntiles; kt++) {
        const int s0 = kt * 64;
        if (kt + 1 < ntiles) stage(kt + 1, cur ^ 1);   // hidden under compute

        // ---- S = Q K^T (swizzled kf reads)
        f32x4 sf[4];
        #pragma unroll
        for (int nb = 0; nb < 4; nb++)
            #pragma unroll
            for (int r = 0; r < 4; r++) sf[nb][r] = 0.0f;
        #pragma unroll
        for (int c = 0; c < 4; c++) {
            #pragma unroll
            for (int nb = 0; nb < 4; nb++) {
                const int u = (c * 4 + quad) ^ (l16 & 7);
                bf16x8 kf = *(const bf16x8*)
                    &sm.a.Ks[cur][(nb * 16 + l16) * 128 + u * 8];
                sf[nb] = __builtin_amdgcn_mfma_f32_16x16x32_bf16(
                    qf[c], kf, sf[nb], 0, 0, 0);
            }
        }

        // ---- scale + causal mask, log2 domain
        const bool need_mask = (s0 + 63 > wrow0);
        {
            const int qr0 = wrow0 + quad * 4;
            #pragma unroll
            for (int nb = 0; nb < 4; nb++) {
                const int kcol = s0 + nb * 16 + l16;
                #pragma unroll
                for (int r = 0; r < 4; r++) {
                    float s = sf[nb][r] * scale2;
                    if (need_mask && kcol > qr0 + r) s += mneg2;
                    sf[nb][r] = s;
                }
            }
        }

        // ---- online softmax (16-lane max reduce; lr partials; deferred
        //      rescale when no row max grew)
        {
            float mt4[4];
            #pragma unroll
            for (int r = 0; r < 4; r++) {
                float mt = fmaxf(fmaxf(sf[0][r], sf[1][r]),
                                 fmaxf(sf[2][r], sf[3][r]));
                mt = fmaxf(mt, __shfl_xor(mt, 1));
                mt = fmaxf(mt, __shfl_xor(mt, 2));
                mt = fmaxf(mt, __shfl_xor(mt, 4));
                mt = fmaxf(mt, __shfl_xor(mt, 8));
                mt4[r] = mt;
            }
            const bool grew = (mt4[0] > mr[0]) || (mt4[1] > mr[1]) ||
                              (mt4[2] > mr[2]) || (mt4[3] > mr[3]);
            if (__any(grew)) {
                float alpha[4];
                #pragma unroll
                for (int r = 0; r < 4; r++) {
                    const float mnew = fmaxf(mr[r], mt4[r]);
                    alpha[r] = __builtin_amdgcn_exp2f(mr[r] - mnew);
                    mr[r] = mnew;
                    lr[r] *= alpha[r];
                }
                #pragma unroll
                for (int db = 0; db < 8; db++)
                    #pragma unroll
                    for (int r = 0; r < 4; r++) of[db][r] *= alpha[r];
            }
            #pragma unroll
            for (int r = 0; r < 4; r++) {
                float rs = 0.0f;
                #pragma unroll
                for (int nb = 0; nb < 4; nb++) {
                    float p = __builtin_amdgcn_exp2f(sf[nb][r] - mr[r]);
                    sf[nb][r] = p;
                    rs += p;
                }
                lr[r] += rs;       // per-lane partial; reduced in epilogue
            }

            // P: C-layout -> wave-private LDS [m][s]
            #pragma unroll
            for (int nb = 0; nb < 4; nb++)
                #pragma unroll
                for (int r = 0; r < 4; r++)
                    Pw[(quad * 4 + r) * PSTR + nb * 16 + l16] = f2b(sf[nb][r]);
        }

        // ---- O += P V (swizzled vf reads from row-readable Vs[d][s])
        #pragma unroll
        for (int kc = 0; kc < 2; kc++) {
            bf16x8 pf = *(const bf16x8*)&Pw[l16 * PSTR + kc * 32 + quad * 8];
            #pragma unroll
            for (int db = 0; db < 8; db++) {
                const int u = (kc * 4 + quad) ^ (l16 & 7);
                bf16x8 vf = *(const bf16x8*)
                    &sm.a.Vs[cur][(db * 16 + l16) * 64 + u * 8];
                of[db] = __builtin_amdgcn_mfma_f32_16x16x32_bf16(
                    pf, vf, of[db], 0, 0, 0);
            }
        }

        __syncthreads();           // drains my stage(t+1) + all waves done
        cur ^= 1;
    }

    // ---- epilogue: lane-reduce lr, normalize, LDS transpose, float4 stores.
    float* Ow = sm.Ow + w * 16 * OSTR;     // wave-private 16x132 fp32
    float inv[4];
    #pragma unroll
    for (int r = 0; r < 4; r++) {
        float ls = lr[r];
        ls += __shfl_xor(ls, 1);
        ls += __shfl_xor(ls, 2);
        ls += __shfl_xor(ls, 4);
        ls += __shfl_xor(ls, 8);
        inv[r] = 1.0f / ls;
    }
    #pragma unroll
    for (int db = 0; db < 8; db++)
        #pragma unroll
        for (int r = 0; r < 4; r++)
            Ow[(quad * 4 + r) * OSTR + db * 16 + l16] = of[db][r] * inv[r];
    #pragma unroll
    for (int rg = 0; rg < 4; rg++) {
        const int rowl = rg * 4 + quad;
        float* op = out + ((size_t)(b * S_ + wrow0 + rowl)) * E_ + h * HD_;
        #pragma unroll
        for (int u = 0; u < 2; u++) {
            float4 v4 = *(const float4*)&Ow[rowl * OSTR + u * 64 + l16 * 4];
            *(float4*)(op + u * 64 + l16 * 4) = v4;
        }
    }
}

// ---------------------------------------------------------------------------
extern "C" void kernel_launch(void* const* d_in, const int* in_sizes, int n_in,
                              void* d_out, int out_size, void* d_ws, size_t ws_size,
                              hipStream_t stream)
{
    const float* x    = (const float*)d_in[0];   // fp32 (B,S,E)
    const float* W    = (const float*)d_in[1];   // fp32 (6144,2048)
    const float* bias = (const float*)d_in[2];   // fp32 (6144,)
    float* out = (float*)d_out;                  // fp32 (B,S,E)

    const size_t per = (size_t)B_ * NH_ * S_ * HD_;               // 8388608
    unsigned short* qb = (unsigned short*)d_ws;                   // [B][NH][S][HD]
    unsigned short* kb = qb + per;                                // [B][NH][S][HD]
    unsigned short* vt = kb + per;                                // [B][NH][HD][S]
    unsigned short* Xb = vt + per;                                // bf16 X
    unsigned short* Wb = Xb + (size_t)XN_;                        // bf16 W

    const int cvt_elems = XN_ + NQKV_ * E_;                       // 20971520
    cvt_bf16<<<cvt_elems / (256 * 8), 256, 0, stream>>>(x, W, Xb);

    dim3 gemm_grid((M_ / 128) * (NQKV_ / 256));                   // 32*24 = 768
    qkv_gemm<<<gemm_grid, 512, 0, stream>>>(Xb, Wb, bias, qb, kb, vt);

    attn_mfma<<<dim3(32 * 32), 256, 0, stream>>>(qb, kb, vt, out);
}